// Round 8
// baseline (522.173 us; speedup 1.0000x reference)
//
#include <hip/hip_runtime.h>
#include <hip/hip_bf16.h>
#include <cstdint>

#define N_NODES 50000
#define N_EDGES 800000

// ---------------------------------------------------------------------------
// feat = X @ W  and el/er = per-head attention dots.
// 256 threads, tile 64 rows x DOUT cols; thread (tr,tc) owns 4 rows x CN cols.
// T14 async staging: global loads for phase p+1 issued into registers before
// computing phase p from LDS; regs->LDS after the barrier (latency hidden
// under ~2000 cyc of FMAs). KP=32 -> 25.9 KB LDS.
template<int DIN, int DOUT, int F>
__global__ __launch_bounds__(256) void gemm_attn(
    const float* __restrict__ X, const float* __restrict__ W,
    const float* __restrict__ al, const float* __restrict__ ar,
    float* __restrict__ feat, float* __restrict__ el, float* __restrict__ er, int N)
{
    constexpr int KP   = 32;            // k-phase size
    constexpr int NPH  = DIN / KP;      // 8 for L0, 4 for L1/L2
    constexpr int CN   = DOUT / 16;     // cols per thread (8 or 4)
    constexpr int H    = DOUT / F;
    constexpr int XSTR = KP + 4;        // 36
    constexpr int WSTR = KP * CN + 4;
    constexpr int XL   = 64 * (KP / 4) / 256;        // x float4 loads/thread = 2
    constexpr int WRT  = KP / 16;                    // w k-rows per thread = 2
    constexpr int WJ   = CN / 4;                     // float4 per k-row = 2 or 1

    __shared__ float xs[64][XSTR];
    __shared__ float ws[16][WSTR];

    const int tid  = threadIdx.x;
    const int tr   = tid >> 4;          // row group
    const int tc   = tid & 15;          // col group
    const int krow = tid >> 4;          // k-slot for W staging
    const int row0 = blockIdx.x * 64;

    float4 xr[XL];
    float4 wr[WRT][WJ];

    auto issueLoads = [&](int ph) {
#pragma unroll
        for (int i = 0; i < XL; ++i) {
            int s = tid + i * 256;
            int r = s >> 3, q = s & 7;          // 8 float4 per row
            int rr = min(row0 + r, N - 1);
            xr[i] = *reinterpret_cast<const float4*>(
                &X[(size_t)rr * DIN + ph * KP + 4 * q]);
        }
#pragma unroll
        for (int i = 0; i < WRT; ++i) {
            int k = krow + 16 * i;
#pragma unroll
            for (int j = 0; j < WJ; ++j)
                wr[i][j] = *reinterpret_cast<const float4*>(
                    &W[(size_t)(ph * KP + k) * DOUT + tc * CN + 4 * j]);
        }
    };
    auto writeLDS = [&]() {
#pragma unroll
        for (int i = 0; i < XL; ++i) {
            int s = tid + i * 256;
            int r = s >> 3, q = s & 7;
            *reinterpret_cast<float4*>(&xs[r][4 * q]) = xr[i];
        }
#pragma unroll
        for (int i = 0; i < WRT; ++i) {
            int k = krow + 16 * i;
#pragma unroll
            for (int j = 0; j < WJ; ++j)
                *reinterpret_cast<float4*>(&ws[tc][k * CN + 4 * j]) = wr[i][j];
        }
    };

    float acc[4][CN];
#pragma unroll
    for (int r = 0; r < 4; ++r)
#pragma unroll
        for (int c = 0; c < CN; ++c) acc[r][c] = 0.f;

    issueLoads(0);
    writeLDS();
    __syncthreads();

    for (int ph = 0; ph < NPH; ++ph) {
        if (ph + 1 < NPH) issueLoads(ph + 1);   // in flight during compute

#pragma unroll
        for (int k4 = 0; k4 < KP / 4; ++k4) {
            float4 xv[4];
#pragma unroll
            for (int rr = 0; rr < 4; ++rr)
                xv[rr] = *reinterpret_cast<const float4*>(&xs[tr * 4 + rr][k4 * 4]);
            float wv[4][CN];
#pragma unroll
            for (int kk = 0; kk < 4; ++kk)
#pragma unroll
                for (int j = 0; j < WJ; ++j)
                    *reinterpret_cast<float4*>(&wv[kk][4 * j]) =
                        *reinterpret_cast<const float4*>(&ws[tc][(k4 * 4 + kk) * CN + 4 * j]);
#pragma unroll
            for (int kk = 0; kk < 4; ++kk)
#pragma unroll
                for (int rr = 0; rr < 4; ++rr) {
                    const float xk = (kk == 0) ? xv[rr].x : (kk == 1) ? xv[rr].y
                                   : (kk == 2) ? xv[rr].z : xv[rr].w;
#pragma unroll
                    for (int c = 0; c < CN; ++c)
                        acc[rr][c] = fmaf(xk, wv[kk][c], acc[rr][c]);
                }
        }
        __syncthreads();                        // all waves done reading LDS
        if (ph + 1 < NPH) {
            writeLDS();                         // vmcnt drain hidden by compute
            __syncthreads();
        }
    }

    // ---- attention dots: thread-local partial + shfl reduce over F/CN lanes ----
    constexpr int RW = F / CN;          // 2 for L0/L1, 16 for L2
    float alv[CN], arv[CN];
#pragma unroll
    for (int c = 0; c < CN; ++c) { alv[c] = al[tc * CN + c]; arv[c] = ar[tc * CN + c]; }

#pragma unroll
    for (int rr = 0; rr < 4; ++rr) {
        int row = row0 + tr * 4 + rr;
        float pl = 0.f, pr = 0.f;
#pragma unroll
        for (int c = 0; c < CN; ++c) {
            pl = fmaf(acc[rr][c], alv[c], pl);
            pr = fmaf(acc[rr][c], arv[c], pr);
        }
#pragma unroll
        for (int off = 1; off < RW; off <<= 1) {
            pl += __shfl_xor(pl, off);
            pr += __shfl_xor(pr, off);
        }
        if (row < N && (tc % RW) == 0) {
            int h = (tc * CN) / F;
            el[(size_t)row * H + h] = pl;
            er[(size_t)row * H + h] = pr;
        }
    }

    // ---- feat store ----
#pragma unroll
    for (int rr = 0; rr < 4; ++rr) {
        int row = row0 + tr * 4 + rr;
        if (row < N) {
#pragma unroll
            for (int j = 0; j < CN / 4; ++j) {
                float4 v = make_float4(acc[rr][4 * j], acc[rr][4 * j + 1],
                                       acc[rr][4 * j + 2], acc[rr][4 * j + 3]);
                *reinterpret_cast<float4*>(&feat[(size_t)row * DOUT + tc * CN + 4 * j]) = v;
            }
        }
    }
}

// ---------------------------------------------------------------------------
// CSR build (dst-sorted), shared by all 3 layers
__global__ void zero_ints(int* __restrict__ a, int n)
{
    int i = blockIdx.x * blockDim.x + threadIdx.x;
    if (i < n) a[i] = 0;
}

__global__ void hist_deg(const int* __restrict__ dst, int* __restrict__ deg)
{
    int e = blockIdx.x * blockDim.x + threadIdx.x;
    if (e < N_EDGES) atomicAdd(&deg[dst[e]], 1);
}

__global__ __launch_bounds__(1024) void scan_offsets(
    const int* __restrict__ deg, int* __restrict__ offs, int n)
{
    __shared__ int wtot[16], wincl[16];
    __shared__ int carry_s;
    const int tid = threadIdx.x;
    const int lane = tid & 63, wid = tid >> 6;
    if (tid == 0) carry_s = 0;
    __syncthreads();
    for (int base = 0; base < n; base += 1024) {
        int i = base + tid;
        int v = (i < n) ? deg[i] : 0;
        int x = v;
#pragma unroll
        for (int off = 1; off < 64; off <<= 1) {
            int t = __shfl_up(x, off);
            if (lane >= off) x += t;
        }
        if (lane == 63) wtot[wid] = x;
        __syncthreads();
        if (tid < 16) {
            int wx = wtot[tid];
#pragma unroll
            for (int off = 1; off < 16; off <<= 1) {
                int t = __shfl_up(wx, off);
                if (tid >= off) wx += t;
            }
            wincl[tid] = wx;
        }
        __syncthreads();
        int waveExcl = (wid == 0) ? 0 : wincl[wid - 1];
        if (i < n) offs[i] = carry_s + waveExcl + (x - v);
        int total = wincl[15];
        __syncthreads();
        if (tid == 0) carry_s += total;
        __syncthreads();
    }
    if (threadIdx.x == 0) offs[n] = carry_s;
}

__global__ void build_csr(const int* __restrict__ src, const int* __restrict__ dst,
                          const int* __restrict__ offs, int* __restrict__ cursor,
                          int* __restrict__ csr_src)
{
    int e = blockIdx.x * blockDim.x + threadIdx.x;
    if (e >= N_EDGES) return;
    int d = dst[e];
    int p = offs[d] + atomicAdd(&cursor[d], 1);
    csr_src[p] = src[e];
}

// ---------------------------------------------------------------------------
// Fused softmax + aggregation per dst node. One wave per node.
// Fast path (deg <= MAXCH*EPC): all csr/el gathers issued upfront, single
// max-tree + sum-tree, 1/s folded into ex, branchless zero-padded batches.
// Generic online-softmax fallback for rare high-degree nodes.
template<int H, int F, bool ACT>
__global__ __launch_bounds__(256) void node_flash_agg(
    const int* __restrict__ offs, const int* __restrict__ csr_src,
    const float* __restrict__ el, const float* __restrict__ er,
    const float* __restrict__ feat, const float* __restrict__ bias,
    float* __restrict__ out, int N)
{
    constexpr int D = H * F;
    constexpr int CPT = D / 64;             // 2 or 1
    constexpr int EPC = 64 / H;             // 8 or 64
    constexpr int MAXCH = (H == 8) ? 6 : 1; // fast path covers deg<=48 / 64
    constexpr int SB = 8;

    const int wid = threadIdx.x >> 6;
    const int lane = threadIdx.x & 63;
    const int n = blockIdx.x * 4 + wid;
    if (n >= N) return;

    const int beg = offs[n];
    const int deg = offs[n + 1] - beg;

    const int comp0 = CPT * lane;
    const int myhead = comp0 / F;

    if (deg == 0) {
#pragma unroll
        for (int c = 0; c < CPT; ++c) {
            float v = bias[comp0 + c];
            if (ACT) v = (v > 0.f) ? v : expm1f(v);
            out[(size_t)n * D + comp0 + c] = v;
        }
        return;
    }

    const int h = lane % H;
    const int esub = lane / H;
    const float erd = er[(size_t)n * H + h];

    float acc[CPT];
#pragma unroll
    for (int c = 0; c < CPT; ++c) acc[c] = 0.f;

    if (deg <= MAXCH * EPC) {
        // ================= fast path =================
        const int nch = (deg + EPC - 1) / EPC;      // wave-uniform
        int sreg[MAXCH];
        float ex[MAXCH];

#pragma unroll
        for (int j = 0; j < MAXCH; ++j) {
            if (j < nch) {
                sreg[j] = csr_src[beg + min(j * EPC + esub, deg - 1)];
                ex[j] = el[(size_t)sreg[j] * H + h];
            }
        }
        float m = -1e30f;
#pragma unroll
        for (int j = 0; j < MAXCH; ++j) {
            if (j < nch) {
                float v = ex[j] + erd;
                v = (v > 0.f) ? v : 0.2f * v;       // leaky_relu 0.2
                v = (j * EPC + esub < deg) ? v : -1e30f;
                ex[j] = v;
                m = fmaxf(m, v);
            }
        }
#pragma unroll
        for (int off = H; off < 64; off <<= 1)
            m = fmaxf(m, __shfl_xor(m, off));
        float s = 0.f;
#pragma unroll
        for (int j = 0; j < MAXCH; ++j) {
            if (j < nch) { ex[j] = __expf(ex[j] - m); s += ex[j]; }
        }
#pragma unroll
        for (int off = H; off < 64; off <<= 1)
            s += __shfl_xor(s, off);
        const float inv = 1.f / s;
#pragma unroll
        for (int j = 0; j < MAXCH; ++j)
            if (j < nch) ex[j] *= inv;              // normalize upfront

#pragma unroll
        for (int j = 0; j < MAXCH; ++j) {
            if (j < nch) {
#pragma unroll
                for (int g = 0; g < EPC; g += SB) {
                    if (j * EPC + g < deg) {        // uniform batch guard
                        float fv[SB][CPT];
#pragma unroll
                        for (int ii = 0; ii < SB; ++ii) {
                            int sl = __shfl(sreg[j], (g + ii) * H);
                            if constexpr (CPT == 2) {
                                float2 t = *reinterpret_cast<const float2*>(
                                    &feat[(size_t)sl * D + comp0]);
                                fv[ii][0] = t.x; fv[ii][1] = t.y;
                            } else {
                                fv[ii][0] = feat[(size_t)sl * D + comp0];
                            }
                        }
#pragma unroll
                        for (int ii = 0; ii < SB; ++ii) {
                            float exb = __shfl(ex[j], (g + ii) * H + myhead);
#pragma unroll
                            for (int c = 0; c < CPT; ++c)
                                acc[c] = fmaf(fv[ii][c], exb, acc[c]);
                        }
                    }
                }
            }
        }
#pragma unroll
        for (int c = 0; c < CPT; ++c) {
            float v = acc[c] + bias[comp0 + c];
            if (ACT) v = (v > 0.f) ? v : expm1f(v);
            acc[c] = v;
        }
    } else {
        // ================= generic online fallback =================
        float m_run = -1e30f, s_run = 0.f;
        int sN = csr_src[beg + min(esub, deg - 1)];
        float elN = el[(size_t)sN * H + h];

        for (int base = 0; base < deg; base += EPC) {
            const int s_mine = sN;
            const float elv = elN;
            const int nb = base + EPC;
            if (nb < deg) {
                sN = csr_src[beg + min(nb + esub, deg - 1)];
                elN = el[(size_t)sN * H + h];
            }
            float v = elv + erd;
            v = (v > 0.f) ? v : 0.2f * v;
            float logit = (base + esub < deg) ? v : -1e30f;

            float cmax = logit;
#pragma unroll
            for (int off = H; off < 64; off <<= 1)
                cmax = fmaxf(cmax, __shfl_xor(cmax, off));
            float nm = fmaxf(m_run, cmax);
            float scale = __expf(m_run - nm);
            float ex = __expf(logit - nm);
            float csum = ex;
#pragma unroll
            for (int off = H; off < 64; off <<= 1)
                csum += __shfl_xor(csum, off);
            s_run = s_run * scale + csum;
            m_run = nm;

            const float sc = __shfl(scale, myhead);
#pragma unroll
            for (int c = 0; c < CPT; ++c) acc[c] *= sc;

            const int active = min(EPC, deg - base);
            for (int g = 0; g < active; g += SB) {
                float fv[SB][CPT];
#pragma unroll
                for (int ii = 0; ii < SB; ++ii) {
                    int sl = __shfl(s_mine, (g + ii) * H);
                    if constexpr (CPT == 2) {
                        float2 t = *reinterpret_cast<const float2*>(
                            &feat[(size_t)sl * D + comp0]);
                        fv[ii][0] = t.x; fv[ii][1] = t.y;
                    } else {
                        fv[ii][0] = feat[(size_t)sl * D + comp0];
                    }
                }
#pragma unroll
                for (int ii = 0; ii < SB; ++ii) {
                    float exb = __shfl(ex, (g + ii) * H + myhead);
#pragma unroll
                    for (int c = 0; c < CPT; ++c)
                        acc[c] = fmaf(fv[ii][c], exb, acc[c]);
                }
            }
        }
        const float invb = __shfl(1.f / s_run, myhead);
#pragma unroll
        for (int c = 0; c < CPT; ++c) {
            float v = acc[c] * invb + bias[comp0 + c];
            if (ACT) v = (v > 0.f) ? v : expm1f(v);
            acc[c] = v;
        }
    }

    if constexpr (CPT == 2) {
        *reinterpret_cast<float2*>(&out[(size_t)n * D + comp0]) =
            make_float2(acc[0], acc[1]);
    } else {
        out[(size_t)n * D + comp0] = acc[0];
    }
}

// ---------------------------------------------------------------------------
extern "C" void kernel_launch(void* const* d_in, const int* in_sizes, int n_in,
                              void* d_out, int out_size, void* d_ws, size_t ws_size,
                              hipStream_t stream)
{
    const float* x   = (const float*)d_in[0];
    const int*   src = (const int*)d_in[1];
    const int*   dst = (const int*)d_in[2];
    const float* W0  = (const float*)d_in[3];
    const float* al0 = (const float*)d_in[4];
    const float* ar0 = (const float*)d_in[5];
    const float* b0  = (const float*)d_in[6];
    const float* W1  = (const float*)d_in[7];
    const float* al1 = (const float*)d_in[8];
    const float* ar1 = (const float*)d_in[9];
    const float* b1  = (const float*)d_in[10];
    const float* W2  = (const float*)d_in[11];
    const float* al2 = (const float*)d_in[12];
    const float* ar2 = (const float*)d_in[13];
    const float* b2  = (const float*)d_in[14];
    float* out = (float*)d_out;

    const int N = N_NODES, E = N_EDGES;

    float* ws   = (float*)d_ws;
    float* feat = ws;                         // N*128
    float* hbuf = feat + (size_t)N * 128;     // N*128
    float* elb  = hbuf + (size_t)N * 128;     // N*8
    float* erb  = elb + (size_t)N * 8;        // N*8
    int* ibase   = (int*)(erb + (size_t)N * 8);
    int* deg     = ibase;                     // N
    int* cursor  = deg + N;                   // N
    int* offs    = cursor + N;                // N+1
    int* csr_src = offs + N + 1;              // E

    const int TB = 256;
    const int gb_rows64 = (N + 63) / 64;
    const int gb_edges  = (E + TB - 1) / TB;
    const int gb_nodes  = (N + 3) / 4;

    // ---- CSR build (shared by all 3 layers) ----
    zero_ints<<<(2 * N + TB - 1) / TB, TB, 0, stream>>>(deg, 2 * N);
    hist_deg<<<gb_edges, TB, 0, stream>>>(dst, deg);
    scan_offsets<<<1, 1024, 0, stream>>>(deg, offs, N);
    build_csr<<<gb_edges, TB, 0, stream>>>(src, dst, offs, cursor, csr_src);

    // ---- layer 0: 256 -> 8 heads x 16, ELU ----
    gemm_attn<256, 128, 16><<<gb_rows64, 256, 0, stream>>>(x, W0, al0, ar0, feat, elb, erb, N);
    node_flash_agg<8, 16, true><<<gb_nodes, 256, 0, stream>>>(
        offs, csr_src, elb, erb, feat, b0, hbuf, N);

    // ---- layer 1: 128 -> 8 heads x 16, ELU ----
    gemm_attn<128, 128, 16><<<gb_rows64, 256, 0, stream>>>(hbuf, W1, al1, ar1, feat, elb, erb, N);
    node_flash_agg<8, 16, true><<<gb_nodes, 256, 0, stream>>>(
        offs, csr_src, elb, erb, feat, b1, hbuf, N);

    // ---- layer 2: 128 -> 1 head x 64, no act ----
    gemm_attn<128, 64, 64><<<gb_rows64, 256, 0, stream>>>(hbuf, W2, al2, ar2, feat, elb, erb, N);
    node_flash_agg<1, 64, false><<<gb_nodes, 256, 0, stream>>>(
        offs, csr_src, elb, erb, feat, b2, out, N);
}

// Round 9
// 405.942 us; speedup vs baseline: 1.2863x; 1.2863x over previous
//
#include <hip/hip_runtime.h>
#include <hip/hip_bf16.h>
#include <cstdint>

#define N_NODES 50000
#define N_EDGES 800000

// ---------------------------------------------------------------------------
// feat = X @ W  and el/er = per-head attention dots.
// Block: 256 threads, tile 64 rows x DOUT cols. Thread (tr,tc) = (tid/16,
// tid%16) owns rows tr*4..+3 and cols tc*CN..+CN-1 (CN = DOUT/16).
// [R6-proven: 65.6us L0, 88 VGPR. R8's reg-staged variant hit 220 VGPR ->
//  occupancy collapse; do not re-introduce register staging here.]
template<int DIN, int DOUT, int F>
__global__ __launch_bounds__(256) void gemm_attn(
    const float* __restrict__ X, const float* __restrict__ W,
    const float* __restrict__ al, const float* __restrict__ ar,
    float* __restrict__ feat, float* __restrict__ el, float* __restrict__ er, int N)
{
    constexpr int KP   = 64;            // k-phase size
    constexpr int NPH  = DIN / KP;      // phases
    constexpr int CN   = DOUT / 16;     // cols per thread (8 or 4)
    constexpr int H    = DOUT / F;
    constexpr int XSTR = KP + 4;        // 68 floats: 16B-aligned rows
    constexpr int WSTR = KP * CN + 4;   // padded w-group stride

    __shared__ float xs[64][XSTR];
    __shared__ float ws[16][WSTR];

    const int tid  = threadIdx.x;
    const int tr   = tid >> 4;          // 0..15 row group
    const int tc   = tid & 15;          // 0..15 col group
    const int row0 = blockIdx.x * 64;

    float acc[4][CN];
#pragma unroll
    for (int r = 0; r < 4; ++r)
#pragma unroll
        for (int c = 0; c < CN; ++c) acc[r][c] = 0.f;

    for (int ph = 0; ph < NPH; ++ph) {
        __syncthreads();
        // stage X: 64 rows x KP cols (float4 coalesced)
#pragma unroll
        for (int i = 0; i < 64 * (KP / 4) / 256; ++i) {
            int s = tid + i * 256;
            int r = s >> 4, q = s & 15;
            int rr = min(row0 + r, N - 1);
            const float4 v = *reinterpret_cast<const float4*>(
                &X[(size_t)rr * DIN + ph * KP + 4 * q]);
            *reinterpret_cast<float4*>(&xs[r][4 * q]) = v;
        }
        // stage W: KP rows x DOUT cols -> ws[group][k*CN + off]
#pragma unroll
        for (int i = 0; i < KP * (DOUT / 4) / 256; ++i) {
            int s = tid + i * 256;
            int k = s / (DOUT / 4), c4 = (s % (DOUT / 4)) * 4;
            const float4 v = *reinterpret_cast<const float4*>(
                &W[(size_t)(ph * KP + k) * DOUT + c4]);
            *reinterpret_cast<float4*>(&ws[c4 / CN][k * CN + (c4 % CN)]) = v;
        }
        __syncthreads();

#pragma unroll 2
        for (int k4 = 0; k4 < KP / 4; ++k4) {
            float4 xv[4];
#pragma unroll
            for (int rr = 0; rr < 4; ++rr)
                xv[rr] = *reinterpret_cast<const float4*>(&xs[tr * 4 + rr][k4 * 4]);
            float wv[4][CN];
#pragma unroll
            for (int kk = 0; kk < 4; ++kk)
#pragma unroll
                for (int j = 0; j < CN / 4; ++j)
                    *reinterpret_cast<float4*>(&wv[kk][4 * j]) =
                        *reinterpret_cast<const float4*>(&ws[tc][(k4 * 4 + kk) * CN + 4 * j]);
#pragma unroll
            for (int kk = 0; kk < 4; ++kk)
#pragma unroll
                for (int rr = 0; rr < 4; ++rr) {
                    const float xk = (kk == 0) ? xv[rr].x : (kk == 1) ? xv[rr].y
                                   : (kk == 2) ? xv[rr].z : xv[rr].w;
#pragma unroll
                    for (int c = 0; c < CN; ++c)
                        acc[rr][c] = fmaf(xk, wv[kk][c], acc[rr][c]);
                }
        }
    }

    // ---- attention dots: thread-local partial + shfl reduce over F/CN lanes ----
    constexpr int RW = F / CN;          // reduce width (2 for L0/L1, 16 for L2)
    float alv[CN], arv[CN];
#pragma unroll
    for (int c = 0; c < CN; ++c) { alv[c] = al[tc * CN + c]; arv[c] = ar[tc * CN + c]; }

#pragma unroll
    for (int rr = 0; rr < 4; ++rr) {
        int row = row0 + tr * 4 + rr;
        float pl = 0.f, pr = 0.f;
#pragma unroll
        for (int c = 0; c < CN; ++c) {
            pl = fmaf(acc[rr][c], alv[c], pl);
            pr = fmaf(acc[rr][c], arv[c], pr);
        }
#pragma unroll
        for (int off = 1; off < RW; off <<= 1) {
            pl += __shfl_xor(pl, off);
            pr += __shfl_xor(pr, off);
        }
        if (row < N && (tc % RW) == 0) {
            int h = (tc * CN) / F;
            el[(size_t)row * H + h] = pl;
            er[(size_t)row * H + h] = pr;
        }
    }

    // ---- feat store (contiguous CN cols per thread) ----
#pragma unroll
    for (int rr = 0; rr < 4; ++rr) {
        int row = row0 + tr * 4 + rr;
        if (row < N) {
#pragma unroll
            for (int j = 0; j < CN / 4; ++j) {
                float4 v = make_float4(acc[rr][4 * j], acc[rr][4 * j + 1],
                                       acc[rr][4 * j + 2], acc[rr][4 * j + 3]);
                *reinterpret_cast<float4*>(&feat[(size_t)row * DOUT + tc * CN + 4 * j]) = v;
            }
        }
    }
}

// ---------------------------------------------------------------------------
// CSR build (dst-sorted), shared by all 3 layers
__global__ void zero_ints(int* __restrict__ a, int n)
{
    int i = blockIdx.x * blockDim.x + threadIdx.x;
    if (i < n) a[i] = 0;
}

__global__ void hist_deg(const int* __restrict__ dst, int* __restrict__ deg)
{
    int e = blockIdx.x * blockDim.x + threadIdx.x;
    if (e < N_EDGES) atomicAdd(&deg[dst[e]], 1);
}

__global__ __launch_bounds__(1024) void scan_offsets(
    const int* __restrict__ deg, int* __restrict__ offs, int n)
{
    __shared__ int wtot[16], wincl[16];
    __shared__ int carry_s;
    const int tid = threadIdx.x;
    const int lane = tid & 63, wid = tid >> 6;
    if (tid == 0) carry_s = 0;
    __syncthreads();
    for (int base = 0; base < n; base += 1024) {
        int i = base + tid;
        int v = (i < n) ? deg[i] : 0;
        int x = v;
#pragma unroll
        for (int off = 1; off < 64; off <<= 1) {
            int t = __shfl_up(x, off);
            if (lane >= off) x += t;
        }
        if (lane == 63) wtot[wid] = x;
        __syncthreads();
        if (tid < 16) {
            int wx = wtot[tid];
#pragma unroll
            for (int off = 1; off < 16; off <<= 1) {
                int t = __shfl_up(wx, off);
                if (tid >= off) wx += t;
            }
            wincl[tid] = wx;
        }
        __syncthreads();
        int waveExcl = (wid == 0) ? 0 : wincl[wid - 1];
        if (i < n) offs[i] = carry_s + waveExcl + (x - v);
        int total = wincl[15];
        __syncthreads();
        if (tid == 0) carry_s += total;
        __syncthreads();
    }
    if (threadIdx.x == 0) offs[n] = carry_s;
}

__global__ void build_csr(const int* __restrict__ src, const int* __restrict__ dst,
                          const int* __restrict__ offs, int* __restrict__ cursor,
                          int* __restrict__ csr_src)
{
    int e = blockIdx.x * blockDim.x + threadIdx.x;
    if (e >= N_EDGES) return;
    int d = dst[e];
    int p = offs[d] + atomicAdd(&cursor[d], 1);
    csr_src[p] = src[e];
}

// ---------------------------------------------------------------------------
// Fused softmax + aggregation per dst node. One wave per node.
// Fast path (deg <= MAXCH*EPC): all csr/el gathers issued upfront, single
// max-tree + sum-tree, 1/s folded into ex, branchless zero-padded batches.
// Generic online-softmax fallback for rare high-degree nodes.
template<int H, int F, bool ACT>
__global__ __launch_bounds__(256) void node_flash_agg(
    const int* __restrict__ offs, const int* __restrict__ csr_src,
    const float* __restrict__ el, const float* __restrict__ er,
    const float* __restrict__ feat, const float* __restrict__ bias,
    float* __restrict__ out, int N)
{
    constexpr int D = H * F;
    constexpr int CPT = D / 64;             // 2 or 1
    constexpr int EPC = 64 / H;             // 8 or 64
    constexpr int MAXCH = (H == 8) ? 6 : 1; // fast path covers deg<=48 / 64
    constexpr int SB = 8;

    const int wid = threadIdx.x >> 6;
    const int lane = threadIdx.x & 63;
    const int n = blockIdx.x * 4 + wid;
    if (n >= N) return;

    const int beg = offs[n];
    const int deg = offs[n + 1] - beg;

    const int comp0 = CPT * lane;
    const int myhead = comp0 / F;

    if (deg == 0) {
#pragma unroll
        for (int c = 0; c < CPT; ++c) {
            float v = bias[comp0 + c];
            if (ACT) v = (v > 0.f) ? v : expm1f(v);
            out[(size_t)n * D + comp0 + c] = v;
        }
        return;
    }

    const int h = lane % H;
    const int esub = lane / H;
    const float erd = er[(size_t)n * H + h];

    float acc[CPT];
#pragma unroll
    for (int c = 0; c < CPT; ++c) acc[c] = 0.f;

    if (deg <= MAXCH * EPC) {
        // ================= fast path =================
        const int nch = (deg + EPC - 1) / EPC;      // wave-uniform
        int sreg[MAXCH];
        float ex[MAXCH];

#pragma unroll
        for (int j = 0; j < MAXCH; ++j) {
            if (j < nch) {
                sreg[j] = csr_src[beg + min(j * EPC + esub, deg - 1)];
                ex[j] = el[(size_t)sreg[j] * H + h];
            }
        }
        float m = -1e30f;
#pragma unroll
        for (int j = 0; j < MAXCH; ++j) {
            if (j < nch) {
                float v = ex[j] + erd;
                v = (v > 0.f) ? v : 0.2f * v;       // leaky_relu 0.2
                v = (j * EPC + esub < deg) ? v : -1e30f;
                ex[j] = v;
                m = fmaxf(m, v);
            }
        }
#pragma unroll
        for (int off = H; off < 64; off <<= 1)
            m = fmaxf(m, __shfl_xor(m, off));
        float s = 0.f;
#pragma unroll
        for (int j = 0; j < MAXCH; ++j) {
            if (j < nch) { ex[j] = __expf(ex[j] - m); s += ex[j]; }
        }
#pragma unroll
        for (int off = H; off < 64; off <<= 1)
            s += __shfl_xor(s, off);
        const float inv = 1.f / s;
#pragma unroll
        for (int j = 0; j < MAXCH; ++j)
            if (j < nch) ex[j] *= inv;              // normalize upfront

#pragma unroll
        for (int j = 0; j < MAXCH; ++j) {
            if (j < nch) {
#pragma unroll
                for (int g = 0; g < EPC; g += SB) {
                    if (j * EPC + g < deg) {        // uniform batch guard
                        float fv[SB][CPT];
#pragma unroll
                        for (int ii = 0; ii < SB; ++ii) {
                            int sl = __shfl(sreg[j], (g + ii) * H);
                            if constexpr (CPT == 2) {
                                float2 t = *reinterpret_cast<const float2*>(
                                    &feat[(size_t)sl * D + comp0]);
                                fv[ii][0] = t.x; fv[ii][1] = t.y;
                            } else {
                                fv[ii][0] = feat[(size_t)sl * D + comp0];
                            }
                        }
#pragma unroll
                        for (int ii = 0; ii < SB; ++ii) {
                            float exb = __shfl(ex[j], (g + ii) * H + myhead);
#pragma unroll
                            for (int c = 0; c < CPT; ++c)
                                acc[c] = fmaf(fv[ii][c], exb, acc[c]);
                        }
                    }
                }
            }
        }
#pragma unroll
        for (int c = 0; c < CPT; ++c) {
            float v = acc[c] + bias[comp0 + c];
            if (ACT) v = (v > 0.f) ? v : expm1f(v);
            acc[c] = v;
        }
    } else {
        // ================= generic online fallback =================
        float m_run = -1e30f, s_run = 0.f;
        int sN = csr_src[beg + min(esub, deg - 1)];
        float elN = el[(size_t)sN * H + h];

        for (int base = 0; base < deg; base += EPC) {
            const int s_mine = sN;
            const float elv = elN;
            const int nb = base + EPC;
            if (nb < deg) {
                sN = csr_src[beg + min(nb + esub, deg - 1)];
                elN = el[(size_t)sN * H + h];
            }
            float v = elv + erd;
            v = (v > 0.f) ? v : 0.2f * v;
            float logit = (base + esub < deg) ? v : -1e30f;

            float cmax = logit;
#pragma unroll
            for (int off = H; off < 64; off <<= 1)
                cmax = fmaxf(cmax, __shfl_xor(cmax, off));
            float nm = fmaxf(m_run, cmax);
            float scale = __expf(m_run - nm);
            float ex = __expf(logit - nm);
            float csum = ex;
#pragma unroll
            for (int off = H; off < 64; off <<= 1)
                csum += __shfl_xor(csum, off);
            s_run = s_run * scale + csum;
            m_run = nm;

            const float sc = __shfl(scale, myhead);
#pragma unroll
            for (int c = 0; c < CPT; ++c) acc[c] *= sc;

            const int active = min(EPC, deg - base);
            for (int g = 0; g < active; g += SB) {
                float fv[SB][CPT];
#pragma unroll
                for (int ii = 0; ii < SB; ++ii) {
                    int sl = __shfl(s_mine, (g + ii) * H);
                    if constexpr (CPT == 2) {
                        float2 t = *reinterpret_cast<const float2*>(
                            &feat[(size_t)sl * D + comp0]);
                        fv[ii][0] = t.x; fv[ii][1] = t.y;
                    } else {
                        fv[ii][0] = feat[(size_t)sl * D + comp0];
                    }
                }
#pragma unroll
                for (int ii = 0; ii < SB; ++ii) {
                    float exb = __shfl(ex, (g + ii) * H + myhead);
#pragma unroll
                    for (int c = 0; c < CPT; ++c)
                        acc[c] = fmaf(fv[ii][c], exb, acc[c]);
                }
            }
        }
        const float invb = __shfl(1.f / s_run, myhead);
#pragma unroll
        for (int c = 0; c < CPT; ++c) {
            float v = acc[c] * invb + bias[comp0 + c];
            if (ACT) v = (v > 0.f) ? v : expm1f(v);
            acc[c] = v;
        }
    }

    if constexpr (CPT == 2) {
        *reinterpret_cast<float2*>(&out[(size_t)n * D + comp0]) =
            make_float2(acc[0], acc[1]);
    } else {
        out[(size_t)n * D + comp0] = acc[0];
    }
}

// ---------------------------------------------------------------------------
extern "C" void kernel_launch(void* const* d_in, const int* in_sizes, int n_in,
                              void* d_out, int out_size, void* d_ws, size_t ws_size,
                              hipStream_t stream)
{
    const float* x   = (const float*)d_in[0];
    const int*   src = (const int*)d_in[1];
    const int*   dst = (const int*)d_in[2];
    const float* W0  = (const float*)d_in[3];
    const float* al0 = (const float*)d_in[4];
    const float* ar0 = (const float*)d_in[5];
    const float* b0  = (const float*)d_in[6];
    const float* W1  = (const float*)d_in[7];
    const float* al1 = (const float*)d_in[8];
    const float* ar1 = (const float*)d_in[9];
    const float* b1  = (const float*)d_in[10];
    const float* W2  = (const float*)d_in[11];
    const float* al2 = (const float*)d_in[12];
    const float* ar2 = (const float*)d_in[13];
    const float* b2  = (const float*)d_in[14];
    float* out = (float*)d_out;

    const int N = N_NODES, E = N_EDGES;

    float* ws   = (float*)d_ws;
    float* feat = ws;                         // N*128
    float* hbuf = feat + (size_t)N * 128;     // N*128
    float* elb  = hbuf + (size_t)N * 128;     // N*8
    float* erb  = elb + (size_t)N * 8;        // N*8
    int* ibase   = (int*)(erb + (size_t)N * 8);
    int* deg     = ibase;                     // N
    int* cursor  = deg + N;                   // N
    int* offs    = cursor + N;                // N+1
    int* csr_src = offs + N + 1;              // E

    const int TB = 256;
    const int gb_rows64 = (N + 63) / 64;
    const int gb_edges  = (E + TB - 1) / TB;
    const int gb_nodes  = (N + 3) / 4;

    // ---- CSR build (shared by all 3 layers) ----
    zero_ints<<<(2 * N + TB - 1) / TB, TB, 0, stream>>>(deg, 2 * N);
    hist_deg<<<gb_edges, TB, 0, stream>>>(dst, deg);
    scan_offsets<<<1, 1024, 0, stream>>>(deg, offs, N);
    build_csr<<<gb_edges, TB, 0, stream>>>(src, dst, offs, cursor, csr_src);

    // ---- layer 0: 256 -> 8 heads x 16, ELU ----
    gemm_attn<256, 128, 16><<<gb_rows64, 256, 0, stream>>>(x, W0, al0, ar0, feat, elb, erb, N);
    node_flash_agg<8, 16, true><<<gb_nodes, 256, 0, stream>>>(
        offs, csr_src, elb, erb, feat, b0, hbuf, N);

    // ---- layer 1: 128 -> 8 heads x 16, ELU ----
    gemm_attn<128, 128, 16><<<gb_rows64, 256, 0, stream>>>(hbuf, W1, al1, ar1, feat, elb, erb, N);
    node_flash_agg<8, 16, true><<<gb_nodes, 256, 0, stream>>>(
        offs, csr_src, elb, erb, feat, b1, hbuf, N);

    // ---- layer 2: 128 -> 1 head x 64, no act ----
    gemm_attn<128, 64, 64><<<gb_rows64, 256, 0, stream>>>(hbuf, W2, al2, ar2, feat, elb, erb, N);
    node_flash_agg<1, 64, false><<<gb_nodes, 256, 0, stream>>>(
        offs, csr_src, elb, erb, feat, b2, out, N);
}

// Round 10
// 399.471 us; speedup vs baseline: 1.3072x; 1.0162x over previous
//
#include <hip/hip_runtime.h>
#include <hip/hip_bf16.h>
#include <cstdint>

#define N_NODES 50000
#define N_EDGES 800000

// ---------------------------------------------------------------------------
// feat = X @ W  and el/er = per-head attention dots.
// 256 threads, tile 32 rows x DOUT cols; thread (tr,tc) owns 2 rows x CN cols.
// 32-row tile -> 1563 blocks (~6/CU, vs 3/CU at 64 rows: grid was the
// occupancy limiter, not LDS). wv loaded per-kk (8 regs, not 32) to stay
// under the 64-VGPR occupancy cliff. KP=32 -> ~21 KB LDS.
template<int DIN, int DOUT, int F>
__global__ __launch_bounds__(256) void gemm_attn(
    const float* __restrict__ X, const float* __restrict__ W,
    const float* __restrict__ al, const float* __restrict__ ar,
    float* __restrict__ feat, float* __restrict__ el, float* __restrict__ er, int N)
{
    constexpr int ROWS = 32;
    constexpr int KP   = 32;
    constexpr int NPH  = DIN / KP;
    constexpr int CN   = DOUT / 16;     // cols per thread (8 or 4)
    constexpr int H    = DOUT / F;
    constexpr int XSTR = KP + 4;        // 36
    constexpr int WSTR = KP * CN + 4;

    __shared__ float xs[ROWS][XSTR];
    __shared__ float ws[16][WSTR];

    const int tid  = threadIdx.x;
    const int tr   = tid >> 4;          // 0..15 row group (2 rows each)
    const int tc   = tid & 15;          // 0..15 col group
    const int row0 = blockIdx.x * ROWS;

    float acc[2][CN];
#pragma unroll
    for (int r = 0; r < 2; ++r)
#pragma unroll
        for (int c = 0; c < CN; ++c) acc[r][c] = 0.f;

    for (int ph = 0; ph < NPH; ++ph) {
        __syncthreads();
        // stage X: 32 rows x KP cols = 256 float4, one per thread
        {
            int r = tid >> 3, q = tid & 7;
            int rr = min(row0 + r, N - 1);
            const float4 v = *reinterpret_cast<const float4*>(
                &X[(size_t)rr * DIN + ph * KP + 4 * q]);
            *reinterpret_cast<float4*>(&xs[r][4 * q]) = v;
        }
        // stage W: KP rows x DOUT cols -> ws[group][k*CN + off]
#pragma unroll
        for (int i = 0; i < KP * (DOUT / 4) / 256; ++i) {
            int s = tid + i * 256;
            int k = s / (DOUT / 4), c4 = (s % (DOUT / 4)) * 4;
            const float4 v = *reinterpret_cast<const float4*>(
                &W[(size_t)(ph * KP + k) * DOUT + c4]);
            *reinterpret_cast<float4*>(&ws[c4 / CN][k * CN + (c4 % CN)]) = v;
        }
        __syncthreads();

#pragma unroll
        for (int k4 = 0; k4 < KP / 4; ++k4) {
            const float4 xv0 = *reinterpret_cast<const float4*>(&xs[tr * 2 + 0][k4 * 4]);
            const float4 xv1 = *reinterpret_cast<const float4*>(&xs[tr * 2 + 1][k4 * 4]);
#pragma unroll
            for (int kk = 0; kk < 4; ++kk) {
                float wv[CN];
#pragma unroll
                for (int j = 0; j < CN / 4; ++j)
                    *reinterpret_cast<float4*>(&wv[4 * j]) =
                        *reinterpret_cast<const float4*>(&ws[tc][(k4 * 4 + kk) * CN + 4 * j]);
                const float x0 = (kk == 0) ? xv0.x : (kk == 1) ? xv0.y
                               : (kk == 2) ? xv0.z : xv0.w;
                const float x1 = (kk == 0) ? xv1.x : (kk == 1) ? xv1.y
                               : (kk == 2) ? xv1.z : xv1.w;
#pragma unroll
                for (int c = 0; c < CN; ++c) {
                    acc[0][c] = fmaf(x0, wv[c], acc[0][c]);
                    acc[1][c] = fmaf(x1, wv[c], acc[1][c]);
                }
            }
        }
    }

    // ---- attention dots: thread-local partial + shfl reduce over F/CN lanes ----
    constexpr int RW = F / CN;          // 2 for L0/L1, 16 for L2
    float alv[CN], arv[CN];
#pragma unroll
    for (int c = 0; c < CN; ++c) { alv[c] = al[tc * CN + c]; arv[c] = ar[tc * CN + c]; }

#pragma unroll
    for (int rr = 0; rr < 2; ++rr) {
        int row = row0 + tr * 2 + rr;
        float pl = 0.f, pr = 0.f;
#pragma unroll
        for (int c = 0; c < CN; ++c) {
            pl = fmaf(acc[rr][c], alv[c], pl);
            pr = fmaf(acc[rr][c], arv[c], pr);
        }
#pragma unroll
        for (int off = 1; off < RW; off <<= 1) {
            pl += __shfl_xor(pl, off);
            pr += __shfl_xor(pr, off);
        }
        if (row < N && (tc % RW) == 0) {
            int h = (tc * CN) / F;
            el[(size_t)row * H + h] = pl;
            er[(size_t)row * H + h] = pr;
        }
    }

    // ---- feat store (contiguous CN cols per thread) ----
#pragma unroll
    for (int rr = 0; rr < 2; ++rr) {
        int row = row0 + tr * 2 + rr;
        if (row < N) {
#pragma unroll
            for (int j = 0; j < CN / 4; ++j) {
                float4 v = make_float4(acc[rr][4 * j], acc[rr][4 * j + 1],
                                       acc[rr][4 * j + 2], acc[rr][4 * j + 3]);
                *reinterpret_cast<float4*>(&feat[(size_t)row * DOUT + tc * CN + 4 * j]) = v;
            }
        }
    }
}

// ---------------------------------------------------------------------------
// CSR build (dst-sorted), shared by all 3 layers
__global__ void zero_ints(int* __restrict__ a, int n)
{
    int i = blockIdx.x * blockDim.x + threadIdx.x;
    if (i < n) a[i] = 0;
}

__global__ void hist_deg(const int* __restrict__ dst, int* __restrict__ deg)
{
    int e = blockIdx.x * blockDim.x + threadIdx.x;
    if (e < N_EDGES) atomicAdd(&deg[dst[e]], 1);
}

__global__ __launch_bounds__(1024) void scan_offsets(
    const int* __restrict__ deg, int* __restrict__ offs, int n)
{
    __shared__ int wtot[16], wincl[16];
    __shared__ int carry_s;
    const int tid = threadIdx.x;
    const int lane = tid & 63, wid = tid >> 6;
    if (tid == 0) carry_s = 0;
    __syncthreads();
    for (int base = 0; base < n; base += 1024) {
        int i = base + tid;
        int v = (i < n) ? deg[i] : 0;
        int x = v;
#pragma unroll
        for (int off = 1; off < 64; off <<= 1) {
            int t = __shfl_up(x, off);
            if (lane >= off) x += t;
        }
        if (lane == 63) wtot[wid] = x;
        __syncthreads();
        if (tid < 16) {
            int wx = wtot[tid];
#pragma unroll
            for (int off = 1; off < 16; off <<= 1) {
                int t = __shfl_up(wx, off);
                if (tid >= off) wx += t;
            }
            wincl[tid] = wx;
        }
        __syncthreads();
        int waveExcl = (wid == 0) ? 0 : wincl[wid - 1];
        if (i < n) offs[i] = carry_s + waveExcl + (x - v);
        int total = wincl[15];
        __syncthreads();
        if (tid == 0) carry_s += total;
        __syncthreads();
    }
    if (threadIdx.x == 0) offs[n] = carry_s;
}

__global__ void build_csr(const int* __restrict__ src, const int* __restrict__ dst,
                          const int* __restrict__ offs, int* __restrict__ cursor,
                          int* __restrict__ csr_src)
{
    int e = blockIdx.x * blockDim.x + threadIdx.x;
    if (e >= N_EDGES) return;
    int d = dst[e];
    int p = offs[d] + atomicAdd(&cursor[d], 1);
    csr_src[p] = src[e];
}

// ---------------------------------------------------------------------------
// Fused softmax + aggregation per dst node. One wave per node.
// Fast path (deg <= MAXCH*EPC): csr/el gathers upfront, one max/sum tree,
// 1/s folded into ex, feat gathers in a 2-deep ping-pong pipeline (fvA/fvB,
// compile-time indices only) -> 16 loads in flight.
template<int H, int F, bool ACT>
__global__ __launch_bounds__(256) void node_flash_agg(
    const int* __restrict__ offs, const int* __restrict__ csr_src,
    const float* __restrict__ el, const float* __restrict__ er,
    const float* __restrict__ feat, const float* __restrict__ bias,
    float* __restrict__ out, int N)
{
    constexpr int D = H * F;
    constexpr int CPT = D / 64;             // 2 or 1
    constexpr int EPC = 64 / H;             // 8 or 64
    constexpr int MAXCH = (H == 8) ? 4 : 1; // fast path: deg<=32 / 64
    constexpr int SB = 8;
    constexpr int NB = MAXCH * EPC / SB;    // feat batches (4 or 8)

    const int wid = threadIdx.x >> 6;
    const int lane = threadIdx.x & 63;
    const int n = blockIdx.x * 4 + wid;
    if (n >= N) return;

    const int beg = offs[n];
    const int deg = offs[n + 1] - beg;

    const int comp0 = CPT * lane;
    const int myhead = comp0 / F;

    if (deg == 0) {
#pragma unroll
        for (int c = 0; c < CPT; ++c) {
            float v = bias[comp0 + c];
            if (ACT) v = (v > 0.f) ? v : expm1f(v);
            out[(size_t)n * D + comp0 + c] = v;
        }
        return;
    }

    const int h = lane % H;
    const int esub = lane / H;
    const float erd = er[(size_t)n * H + h];

    float acc[CPT];
#pragma unroll
    for (int c = 0; c < CPT; ++c) acc[c] = 0.f;

    if (deg <= MAXCH * EPC) {
        // ================= fast path =================
        const int nch = (deg + EPC - 1) / EPC;      // wave-uniform
        int sreg[MAXCH];
        float ex[MAXCH];

#pragma unroll
        for (int j = 0; j < MAXCH; ++j) {
            if (j < nch) {
                sreg[j] = csr_src[beg + min(j * EPC + esub, deg - 1)];
                ex[j] = el[(size_t)sreg[j] * H + h];
            }
        }
        float m = -1e30f;
#pragma unroll
        for (int j = 0; j < MAXCH; ++j) {
            if (j < nch) {
                float v = ex[j] + erd;
                v = (v > 0.f) ? v : 0.2f * v;       // leaky_relu 0.2
                v = (j * EPC + esub < deg) ? v : -1e30f;
                ex[j] = v;
                m = fmaxf(m, v);
            }
        }
#pragma unroll
        for (int off = H; off < 64; off <<= 1)
            m = fmaxf(m, __shfl_xor(m, off));
        float s = 0.f;
#pragma unroll
        for (int j = 0; j < MAXCH; ++j) {
            if (j < nch) { ex[j] = __expf(ex[j] - m); s += ex[j]; }
        }
#pragma unroll
        for (int off = H; off < 64; off <<= 1)
            s += __shfl_xor(s, off);
        const float inv = 1.f / s;
#pragma unroll
        for (int j = 0; j < MAXCH; ++j)
            if (j < nch) ex[j] *= inv;              // normalize upfront

        // ---- weighting: 2-deep ping-pong pipelined gather ----
        float fvA[SB][CPT], fvB[SB][CPT];
        auto ldb = [&](int j, int g, float (&fv)[SB][CPT]) {
#pragma unroll
            for (int ii = 0; ii < SB; ++ii) {
                int sl = __shfl(sreg[j], (g + ii) * H);
                if constexpr (CPT == 2) {
                    float2 t = *reinterpret_cast<const float2*>(
                        &feat[(size_t)sl * D + comp0]);
                    fv[ii][0] = t.x; fv[ii][1] = t.y;
                } else {
                    fv[ii][0] = feat[(size_t)sl * D + comp0];
                }
            }
        };
        auto fmab = [&](int j, int g, float (&fv)[SB][CPT]) {
#pragma unroll
            for (int ii = 0; ii < SB; ++ii) {
                float exb = __shfl(ex[j], (g + ii) * H + myhead);
#pragma unroll
                for (int c = 0; c < CPT; ++c)
                    acc[c] = fmaf(fv[ii][c], exb, acc[c]);
            }
        };

        ldb(0, 0, fvA);                             // prologue
#pragma unroll
        for (int b = 0; b < NB; ++b) {
            if (b * SB < deg) {
                if ((b + 1) * SB < deg) {           // prefetch next batch
                    const int jn = ((b + 1) * SB) / EPC;
                    const int gn = ((b + 1) * SB) % EPC;
                    if ((b & 1) == 0) ldb(jn, gn, fvB);
                    else              ldb(jn, gn, fvA);
                }
                const int j = (b * SB) / EPC;
                const int g = (b * SB) % EPC;
                if ((b & 1) == 0) fmab(j, g, fvA);
                else              fmab(j, g, fvB);
            }
        }
#pragma unroll
        for (int c = 0; c < CPT; ++c) {
            float v = acc[c] + bias[comp0 + c];
            if (ACT) v = (v > 0.f) ? v : expm1f(v);
            acc[c] = v;
        }
    } else {
        // ================= generic online fallback =================
        float m_run = -1e30f, s_run = 0.f;
        int sN = csr_src[beg + min(esub, deg - 1)];
        float elN = el[(size_t)sN * H + h];

        for (int base = 0; base < deg; base += EPC) {
            const int s_mine = sN;
            const float elv = elN;
            const int nb = base + EPC;
            if (nb < deg) {
                sN = csr_src[beg + min(nb + esub, deg - 1)];
                elN = el[(size_t)sN * H + h];
            }
            float v = elv + erd;
            v = (v > 0.f) ? v : 0.2f * v;
            float logit = (base + esub < deg) ? v : -1e30f;

            float cmax = logit;
#pragma unroll
            for (int off = H; off < 64; off <<= 1)
                cmax = fmaxf(cmax, __shfl_xor(cmax, off));
            float nm = fmaxf(m_run, cmax);
            float scale = __expf(m_run - nm);
            float ex = __expf(logit - nm);
            float csum = ex;
#pragma unroll
            for (int off = H; off < 64; off <<= 1)
                csum += __shfl_xor(csum, off);
            s_run = s_run * scale + csum;
            m_run = nm;

            const float sc = __shfl(scale, myhead);
#pragma unroll
            for (int c = 0; c < CPT; ++c) acc[c] *= sc;

            const int active = min(EPC, deg - base);
            for (int g = 0; g < active; g += SB) {
                float fv[SB][CPT];
#pragma unroll
                for (int ii = 0; ii < SB; ++ii) {
                    int sl = __shfl(s_mine, (g + ii) * H);
                    if constexpr (CPT == 2) {
                        float2 t = *reinterpret_cast<const float2*>(
                            &feat[(size_t)sl * D + comp0]);
                        fv[ii][0] = t.x; fv[ii][1] = t.y;
                    } else {
                        fv[ii][0] = feat[(size_t)sl * D + comp0];
                    }
                }
#pragma unroll
                for (int ii = 0; ii < SB; ++ii) {
                    float exb = __shfl(ex, (g + ii) * H + myhead);
#pragma unroll
                    for (int c = 0; c < CPT; ++c)
                        acc[c] = fmaf(fv[ii][c], exb, acc[c]);
                }
            }
        }
        const float invb = __shfl(1.f / s_run, myhead);
#pragma unroll
        for (int c = 0; c < CPT; ++c) {
            float v = acc[c] * invb + bias[comp0 + c];
            if (ACT) v = (v > 0.f) ? v : expm1f(v);
            acc[c] = v;
        }
    }

    if constexpr (CPT == 2) {
        *reinterpret_cast<float2*>(&out[(size_t)n * D + comp0]) =
            make_float2(acc[0], acc[1]);
    } else {
        out[(size_t)n * D + comp0] = acc[0];
    }
}

// ---------------------------------------------------------------------------
extern "C" void kernel_launch(void* const* d_in, const int* in_sizes, int n_in,
                              void* d_out, int out_size, void* d_ws, size_t ws_size,
                              hipStream_t stream)
{
    const float* x   = (const float*)d_in[0];
    const int*   src = (const int*)d_in[1];
    const int*   dst = (const int*)d_in[2];
    const float* W0  = (const float*)d_in[3];
    const float* al0 = (const float*)d_in[4];
    const float* ar0 = (const float*)d_in[5];
    const float* b0  = (const float*)d_in[6];
    const float* W1  = (const float*)d_in[7];
    const float* al1 = (const float*)d_in[8];
    const float* ar1 = (const float*)d_in[9];
    const float* b1  = (const float*)d_in[10];
    const float* W2  = (const float*)d_in[11];
    const float* al2 = (const float*)d_in[12];
    const float* ar2 = (const float*)d_in[13];
    const float* b2  = (const float*)d_in[14];
    float* out = (float*)d_out;

    const int N = N_NODES, E = N_EDGES;

    float* ws   = (float*)d_ws;
    float* feat = ws;                         // N*128
    float* hbuf = feat + (size_t)N * 128;     // N*128
    float* elb  = hbuf + (size_t)N * 128;     // N*8
    float* erb  = elb + (size_t)N * 8;        // N*8
    int* ibase   = (int*)(erb + (size_t)N * 8);
    int* deg     = ibase;                     // N
    int* cursor  = deg + N;                   // N
    int* offs    = cursor + N;                // N+1
    int* csr_src = offs + N + 1;              // E

    const int TB = 256;
    const int gb_rows32 = (N + 31) / 32;
    const int gb_edges  = (E + TB - 1) / TB;
    const int gb_nodes  = (N + 3) / 4;

    // ---- CSR build (shared by all 3 layers) ----
    zero_ints<<<(2 * N + TB - 1) / TB, TB, 0, stream>>>(deg, 2 * N);
    hist_deg<<<gb_edges, TB, 0, stream>>>(dst, deg);
    scan_offsets<<<1, 1024, 0, stream>>>(deg, offs, N);
    build_csr<<<gb_edges, TB, 0, stream>>>(src, dst, offs, cursor, csr_src);

    // ---- layer 0: 256 -> 8 heads x 16, ELU ----
    gemm_attn<256, 128, 16><<<gb_rows32, 256, 0, stream>>>(x, W0, al0, ar0, feat, elb, erb, N);
    node_flash_agg<8, 16, true><<<gb_nodes, 256, 0, stream>>>(
        offs, csr_src, elb, erb, feat, b0, hbuf, N);

    // ---- layer 1: 128 -> 8 heads x 16, ELU ----
    gemm_attn<128, 128, 16><<<gb_rows32, 256, 0, stream>>>(hbuf, W1, al1, ar1, feat, elb, erb, N);
    node_flash_agg<8, 16, true><<<gb_nodes, 256, 0, stream>>>(
        offs, csr_src, elb, erb, feat, b1, hbuf, N);

    // ---- layer 2: 128 -> 1 head x 64, no act ----
    gemm_attn<128, 64, 64><<<gb_rows32, 256, 0, stream>>>(hbuf, W2, al2, ar2, feat, elb, erb, N);
    node_flash_agg<1, 64, false><<<gb_nodes, 256, 0, stream>>>(
        offs, csr_src, elb, erb, feat, b2, out, N);
}